// Round 12
// baseline (113.824 us; speedup 1.0000x reference)
//
#include <hip/hip_runtime.h>

#define OUT_DIM 4096
#define IN_DIM 4096
#define NNZ 327680
#define BNNZ 2048
#define BATCH 512
#define CAP 160            // max nnz slots/row (mean 80, sigma ~9; P(>160)~1e-19; held rounds 1-11)
#define BW 8               // batch columns per slab / block
#define NBT (BATCH / BW)   // 64 b-tiles
#define RPB 256            // rows per spmm block

// fp32 -> bf16 round-to-nearest-even
__device__ __forceinline__ unsigned short f2bf(float f) {
    unsigned int x = __float_as_uint(f);
    x += 0x7fffu + ((x >> 16) & 1u);
    return (unsigned short)(x >> 16);
}

// ---- transpose input [B, IN] fp32 -> inputT2 [B/8][IN][8] bf16 (b-tile-major)
// ---- first 32 blocks also zero the 8192-int region {bias[4096], counts[4096]}
__global__ void transpose_k(const float* __restrict__ in,
                            unsigned short* __restrict__ outT,
                            int* __restrict__ zero_region) {
    const int bid = blockIdx.y * gridDim.x + blockIdx.x;
    const int tid = threadIdx.y * 32 + threadIdx.x;
    if (bid < 32) zero_region[bid * 256 + tid] = 0;

    __shared__ float tile[32][33];
    const int bx = blockIdx.x * 32;  // along IN
    const int by = blockIdx.y * 32;  // along B
    const int tx = threadIdx.x, ty = threadIdx.y;
    for (int i = ty; i < 32; i += 8)
        tile[i][tx] = in[(size_t)(by + i) * IN_DIM + bx + tx];
    __syncthreads();
    for (int i = ty; i < 32; i += 8) {
        const int b = by + tx, col = bx + i;
        outT[((size_t)((b >> 3) * IN_DIM + col) << 3) + (b & 7)] = f2bf(tile[tx][i]);
    }
}

// ------- build per-row slot buckets (slab byte offsets) + sparse-bias scatter
__global__ void build_k(const int* __restrict__ rows, const int* __restrict__ cols,
                        const float* __restrict__ vals, int* __restrict__ counts,
                        int2* __restrict__ slots,
                        const int* __restrict__ b_idx, const float* __restrict__ b_vals,
                        float* __restrict__ bias) {
    int k = blockIdx.x * blockDim.x + threadIdx.x;
    if (k < NNZ) {
        int r = rows[k];
        int p = atomicAdd(&counts[r], 1);
        if (p < CAP)   // byte offset within a slab: col * BW * 2
            slots[(size_t)r * CAP + p] = make_int2(cols[k] * (BW * 2),
                                                   __float_as_int(vals[k]));
    }
    if (k < BNNZ) atomicAdd(&bias[b_idx[k]], b_vals[k]);
}

// --- SpMM via LDS slab: block = 256 rows x 8 b; slab = all 4096 cols x 8 b --
// Gathers hit LDS (69 TB/s) instead of the L2 line-miss path (~4cy/line/CU,
// the measured ~38us limiter that survived MLP (r10) and nt (r11) probes).
// lane = (b-pair pb 0..3, nnz-group jg 0..15); jg partials shfl_xor-reduced.
// tile[256][9]: bank period 32 -> conflict-free store phase, bias fused.
__global__ __launch_bounds__(1024, 8)
void spmm_k(const unsigned short* __restrict__ inputT2, const int* __restrict__ counts,
            const int2* __restrict__ slots, const float* __restrict__ bias,
            float* __restrict__ out) {
    __shared__ unsigned short slab[IN_DIM * BW];   // 64 KB
    __shared__ float tile[RPB][9];                 // 9.2 KB (pad -> period 32)

    const int t = threadIdx.x;
    const int bt = blockIdx.x & (NBT - 1);
    const int rc = blockIdx.x >> 6;                // / NBT
    const int r0 = rc * RPB;

    // stage slab: contiguous 64 KB, fully coalesced dwordx4
    {
        const uint4* src = reinterpret_cast<const uint4*>(
            inputT2 + (size_t)bt * IN_DIM * BW);
        uint4* dst = reinterpret_cast<uint4*>(slab);
#pragma unroll
        for (int i = 0; i < 4; ++i)
            dst[i * 1024 + t] = src[i * 1024 + t];
    }
    __syncthreads();

    const int w = t >> 6;
    const int lane = t & 63;
    const int pb = lane & 3;       // b-pair within slab
    const int jg = lane >> 2;      // 16-wide nnz group
    const int rbase = r0 + w * 16;

    // prefetch this wave's 16 row-counts (1 load + shfl broadcast per row)
    const int mycnt = counts[rbase + (lane & 15)];

    const char* slabB = reinterpret_cast<const char*>(slab);

    for (int i = 0; i < 16; ++i) {
        const int r = rbase + i;
        const int cnt = min(__shfl(mycnt, i, 64), CAP);
        const int2* sl = &slots[(size_t)r * CAP];
        float s0 = 0.f, s1 = 0.f;
#pragma unroll 2
        for (int j0 = 0; j0 < cnt; j0 += 16) {
            const int jj = j0 + jg;
            const int2 sv = (jj < cnt) ? sl[jj] : make_int2(0, 0);
            const unsigned int x = *reinterpret_cast<const unsigned int*>(
                slabB + sv.x + pb * 4);
            const float v = __int_as_float(sv.y);
            s0 = fmaf(v, __uint_as_float(x << 16), s0);
            s1 = fmaf(v, __uint_as_float(x & 0xffff0000u), s1);
        }
        // reduce across the 16 jg groups (lanes sharing pb)
        for (int m = 4; m <= 32; m <<= 1) {
            s0 += __shfl_xor(s0, m, 64);
            s1 += __shfl_xor(s1, m, 64);
        }
        if (jg == 0) {
            tile[w * 16 + i][pb * 2 + 0] = s0;
            tile[w * 16 + i][pb * 2 + 1] = s1;
        }
    }
    __syncthreads();

    // write 8 b x 256 rows, line-coalesced (256 consecutive r per store group)
#pragma unroll
    for (int rep = 0; rep < 2; ++rep) {
        const int idx = rep * 1024 + t;
        const int b = idx >> 8;        // 0..7
        const int rl = idx & 255;
        out[(size_t)(bt * BW + b) * OUT_DIM + r0 + rl] = tile[rl][b] + bias[r0 + rl];
    }
}

extern "C" void kernel_launch(void* const* d_in, const int* in_sizes, int n_in,
                              void* d_out, int out_size, void* d_ws, size_t ws_size,
                              hipStream_t stream) {
    const float* input   = (const float*)d_in[0];
    const int*   w_rows  = (const int*)d_in[1];
    const int*   w_cols  = (const int*)d_in[2];
    const float* w_vals  = (const float*)d_in[3];
    const int*   b_idx   = (const int*)d_in[4];
    const float* b_vals  = (const float*)d_in[5];
    float* out = (float*)d_out;

    char* ws = (char*)d_ws;
    const size_t MB = (size_t)1024 * 1024;
    unsigned short* inputT2 = (unsigned short*)ws;     // 4 MiB (bf16, b-tile-major)
    float* bias   = (float*)(ws + 4 * MB);             // 16 KiB
    int*   counts = (int*)(ws + 4 * MB + 16 * 1024);   // 16 KiB
    int2*  slots  = (int2*)(ws + 4 * MB + 32 * 1024);  // 4096*160*8 = 5 MiB

    dim3 tb(32, 8);
    // zero_region = {bias, counts} contiguous 8192 ints, zeroed by first 32 blocks
    transpose_k<<<dim3(IN_DIM / 32, BATCH / 32), tb, 0, stream>>>(input, inputT2,
                                                                  (int*)bias);

    build_k<<<(NNZ + 255) / 256, 256, 0, stream>>>(w_rows, w_cols, w_vals, counts,
                                                   slots, b_idx, b_vals, bias);

    spmm_k<<<NBT * (OUT_DIM / RPB), 1024, 0, stream>>>(inputT2, counts, slots,
                                                       bias, out);
}

// Round 13
// 109.302 us; speedup vs baseline: 1.0414x; 1.0414x over previous
//
#include <hip/hip_runtime.h>

#define OUT_DIM 4096
#define IN_DIM 4096
#define NNZ 327680
#define BNNZ 2048
#define BATCH 512
#define CAP 160            // max nnz slots/row (mean 80, sigma ~9; P(>160)~1e-19; held rounds 1-12)
#define RT 16              // rows per block in spmm phase
#define NBLK 256
#define NTHR 1024

// LDS reused across phases (max 52 KB)
union SMem {
    struct { float tile[4][32][33]; } a;                       // transpose: 16.9 KB
    struct { int2 slot[RT][CAP]; float tile[RT][BATCH]; } b;   // spmm: 20 KB + 32 KB
};

// fp32 -> bf16 round-to-nearest-even
__device__ __forceinline__ unsigned short f2bf(float f) {
    unsigned int x = __float_as_uint(f);
    x += 0x7fffu + ((x >> 16) & 1u);
    return (unsigned short)(x >> 16);
}

__global__ __launch_bounds__(NTHR, 4)
void fused_k(const float* __restrict__ in,
             const int* __restrict__ w_rows, const int* __restrict__ w_cols,
             const float* __restrict__ w_vals,
             const int* __restrict__ b_idx, const float* __restrict__ b_vals,
             unsigned short* __restrict__ inputT, int2* __restrict__ slots,
             float* __restrict__ bias, int* __restrict__ counts,
             int* __restrict__ bar, float* __restrict__ out) {
    __shared__ SMem u;
    const int tid = threadIdx.x;
    const int bid = blockIdx.x;

    // ---- Phase A1: transpose [B,IN] f32 -> inputT [IN,B] bf16 -------------
    {
        const int g = tid >> 8, tx = tid & 31, ty = (tid >> 5) & 7;
        for (int rep = 0; rep < 2; ++rep) {
            const int job = rep * 1024 + bid * 4 + g;   // 0..2047
            const int bx = (job & 127) << 5;            // IN tile origin
            const int by = (job >> 7) << 5;             // B tile origin
            for (int i = ty; i < 32; i += 8)
                u.a.tile[g][i][tx] = in[(size_t)(by + i) * IN_DIM + bx + tx];
            __syncthreads();
            for (int i = ty; i < 32; i += 8)
                inputT[(size_t)(bx + i) * BATCH + by + tx] = f2bf(u.a.tile[g][tx][i]);
            __syncthreads();
        }
    }

    // ---- Phase A2: build per-row slot buckets (byte offsets) + bias -------
    {
        const int kbase = bid * (NNZ / NBLK);           // 1280 nnz per block
        for (int i = tid; i < NNZ / NBLK; i += NTHR) {
            const int k = kbase + i;
            const int r = w_rows[k];
            const int p = atomicAdd(&counts[r], 1);
            if (p < CAP)
                slots[(size_t)r * CAP + p] =
                    make_int2(w_cols[k] * (BATCH * 2), __float_as_int(w_vals[k]));
        }
        if (tid < BNNZ / NBLK) {                        // 8 bias entries per block
            const int k = bid * (BNNZ / NBLK) + tid;
            atomicAdd(&bias[b_idx[k]], b_vals[k]);
        }
    }

    // ---- Grid barrier: RELAXED polls (r7 polled with agent-ACQUIRE each ----
    // iteration -> per-poll cache invalidates + line bouncing ~ 50 us). -----
    // Scope AGENT on the atomics still routes them to the coherence point, --
    // so relaxed polls see remote increments. One release per block before --
    // arrival (covers this XCD's L2 writeback), one acquire fence after. ----
    __syncthreads();
    if (tid == 0) {
        __threadfence();   // release: write back this block's A-phase stores
        __hip_atomic_fetch_add(bar, 1, __ATOMIC_RELAXED, __HIP_MEMORY_SCOPE_AGENT);
        while (__hip_atomic_load(bar, __ATOMIC_RELAXED, __HIP_MEMORY_SCOPE_AGENT) < NBLK)
            __builtin_amdgcn_s_sleep(8);
    }
    __syncthreads();
    __builtin_amdgcn_fence(__ATOMIC_ACQUIRE, "agent");  // once, after all arrived

    // ---- Phase B: spmm (byte-identical structure to rounds 6/10) ----------
    const int w = tid >> 6;            // wave = row within block
    const int lane = tid & 63;         // lane = 8 batch elems
    const int r0 = bid * RT;
    const int r = r0 + w;

    const int cnt = min(counts[r], CAP);
    for (int i = lane; i < cnt; i += 64)
        u.b.slot[w][i] = slots[(size_t)r * CAP + i];
    // no barrier: wave-private slot rows

    const char* base = (const char*)inputT + lane * 16;

    float a0 = 0.f, a1 = 0.f, a2 = 0.f, a3 = 0.f;
    float a4 = 0.f, a5 = 0.f, a6 = 0.f, a7 = 0.f;
#pragma unroll 4
    for (int j = 0; j < cnt; ++j) {
        const int2 sv = u.b.slot[w][j];
        const uint4 q = *reinterpret_cast<const uint4*>(base + sv.x);
        const float v = __int_as_float(sv.y);
        a0 = fmaf(v, __uint_as_float(q.x << 16), a0);
        a1 = fmaf(v, __uint_as_float(q.x & 0xffff0000u), a1);
        a2 = fmaf(v, __uint_as_float(q.y << 16), a2);
        a3 = fmaf(v, __uint_as_float(q.y & 0xffff0000u), a3);
        a4 = fmaf(v, __uint_as_float(q.z << 16), a4);
        a5 = fmaf(v, __uint_as_float(q.z & 0xffff0000u), a5);
        a6 = fmaf(v, __uint_as_float(q.w << 16), a6);
        a7 = fmaf(v, __uint_as_float(q.w & 0xffff0000u), a7);
    }
    float4* tp = reinterpret_cast<float4*>(&u.b.tile[w][lane * 8]);
    tp[0] = make_float4(a0, a1, a2, a3);
    tp[1] = make_float4(a4, a5, a6, a7);
    __syncthreads();

    // store: thread t -> b = t/4 (+256*k2), r-quad = (t%4)*4; float4 along r
    const int rq = (tid & 3) * 4;
    const float4 bv = *reinterpret_cast<const float4*>(&bias[r0 + rq]);
#pragma unroll
    for (int k2 = 0; k2 < 2; ++k2) {
        const int b = (tid >> 2) + k2 * 256;
        float4 o = make_float4(u.b.tile[rq + 0][b] + bv.x, u.b.tile[rq + 1][b] + bv.y,
                               u.b.tile[rq + 2][b] + bv.z, u.b.tile[rq + 3][b] + bv.w);
        *reinterpret_cast<float4*>(&out[(size_t)b * OUT_DIM + r0 + rq]) = o;
    }
}

extern "C" void kernel_launch(void* const* d_in, const int* in_sizes, int n_in,
                              void* d_out, int out_size, void* d_ws, size_t ws_size,
                              hipStream_t stream) {
    const float* input   = (const float*)d_in[0];
    const int*   w_rows  = (const int*)d_in[1];
    const int*   w_cols  = (const int*)d_in[2];
    const float* w_vals  = (const float*)d_in[3];
    const int*   b_idx   = (const int*)d_in[4];
    const float* b_vals  = (const float*)d_in[5];
    float* out = (float*)d_out;

    char* ws = (char*)d_ws;
    const size_t MB = (size_t)1024 * 1024;
    unsigned short* inputT = (unsigned short*)ws;          // 4 MiB (bf16)
    int2*  slots  = (int2*)(ws + 4 * MB);                  // 4096*160*8 = 5 MiB
    char*  zbase  = ws + 9 * MB;                           // zeroed region:
    int*   bar    = (int*)zbase;                           //   [0,64): barrier
    float* bias   = (float*)(zbase + 64);                  //   16 KiB
    int*   counts = (int*)(zbase + 64 + 16 * 1024);        //   16 KiB

    // zero barrier + bias + counts (one small fill node)
    hipMemsetAsync(zbase, 0, 64 + 32 * 1024, stream);

    fused_k<<<NBLK, NTHR, 0, stream>>>(input, w_rows, w_cols, w_vals, b_idx, b_vals,
                                       inputT, slots, bias, counts, bar, out);
}

// Round 14
// 64.364 us; speedup vs baseline: 1.7684x; 1.6982x over previous
//
#include <hip/hip_runtime.h>

#define OUT_DIM 4096
#define IN_DIM 4096
#define NNZ 327680
#define BNNZ 2048
#define BATCH 512
#define CAP 160            // max nnz slots/row (mean 80, sigma ~9; P(>160)~1e-19; held rounds 1-13)
#define RT 16              // rows per spmm block
#define BCH 256            // batch elems per spmm block (64 lanes x 4)
#define NCHUNK (BATCH / BCH)

// fp32 -> bf16 round-to-nearest-even
__device__ __forceinline__ unsigned short f2bf(float f) {
    unsigned int x = __float_as_uint(f);
    x += 0x7fffu + ((x >> 16) & 1u);
    return (unsigned short)(x >> 16);
}

// ---- transpose input [B, IN] fp32 -> inputT [IN, B] bf16; first 32 blocks ----
// ---- also zero the 8192-int region {bias[4096], counts[4096]}             ----
__global__ void transpose_k(const float* __restrict__ in,
                            unsigned short* __restrict__ outT,
                            int* __restrict__ zero_region) {
    const int bid = blockIdx.y * gridDim.x + blockIdx.x;
    const int tid = threadIdx.y * 32 + threadIdx.x;
    if (bid < 32) zero_region[bid * 256 + tid] = 0;

    __shared__ float tile[32][33];
    const int bx = blockIdx.x * 32;  // along IN
    const int by = blockIdx.y * 32;  // along B
    const int tx = threadIdx.x, ty = threadIdx.y;
    for (int i = ty; i < 32; i += 8)
        tile[i][tx] = in[(size_t)(by + i) * IN_DIM + bx + tx];
    __syncthreads();
    for (int i = ty; i < 32; i += 8)
        outT[(size_t)(bx + i) * BATCH + by + tx] = f2bf(tile[tx][i]);
}

// ------- build per-row slot buckets (byte offsets) + sparse-bias scatter ----
__global__ void build_k(const int* __restrict__ rows, const int* __restrict__ cols,
                        const float* __restrict__ vals, int* __restrict__ counts,
                        int2* __restrict__ slots,
                        const int* __restrict__ b_idx, const float* __restrict__ b_vals,
                        float* __restrict__ bias) {
    int k = blockIdx.x * blockDim.x + threadIdx.x;
    if (k < NNZ) {
        int r = rows[k];
        int p = atomicAdd(&counts[r], 1);
        if (p < CAP)   // byte offset into bf16 inputT row: col * BATCH * 2
            slots[(size_t)r * CAP + p] = make_int2(cols[k] * (BATCH * 2),
                                                   __float_as_int(vals[k]));
    }
    if (k < BNNZ) atomicAdd(&bias[b_idx[k]], b_vals[k]);
}

// --- SpMM: block = 16 rows x 256 b (1024 thr); wave = 1 row, lane = 4 b ----
// r6 structure, ONE change: batch split in 2 chunks -> grid 512 -> 2 blocks/CU
// = 32 waves/CU (r6 had 16), doubling outstanding gathers to hide L2 latency.
// Gather is dwordx2 (8 lines/wave-gather, 2x gathers: same TA total, bytes).
__global__ __launch_bounds__(1024, 8)
void spmm_k(const unsigned short* __restrict__ inputT, const int* __restrict__ counts,
            const int2* __restrict__ slots, const float* __restrict__ bias,
            float* __restrict__ out) {
    const int w = threadIdx.x >> 6;      // wave = row within block
    const int lane = threadIdx.x & 63;   // lane = 4 batch elems
    const int r0 = blockIdx.x * RT;
    const int r = r0 + w;

    __shared__ int2  s_slot[RT][CAP];    // 20 KB, wave-private rows
    __shared__ float tile[RT][BCH];      // 16 KB

    const int cnt = min(counts[r], CAP);
    for (int i = lane; i < cnt; i += 64)
        s_slot[w][i] = slots[(size_t)r * CAP + i];
    // no barrier: wave-private slot rows

    const char* base = (const char*)inputT + blockIdx.y * (BCH * 2) + lane * 8;

    float a0 = 0.f, a1 = 0.f, a2 = 0.f, a3 = 0.f;
#pragma unroll 4
    for (int j = 0; j < cnt; ++j) {
        const int2 sv = s_slot[w][j];
        const uint2 q = *reinterpret_cast<const uint2*>(base + sv.x);
        const float v = __int_as_float(sv.y);
        a0 = fmaf(v, __uint_as_float(q.x << 16), a0);
        a1 = fmaf(v, __uint_as_float(q.x & 0xffff0000u), a1);
        a2 = fmaf(v, __uint_as_float(q.y << 16), a2);
        a3 = fmaf(v, __uint_as_float(q.y & 0xffff0000u), a3);
    }
    *reinterpret_cast<float4*>(&tile[w][lane * 4]) = make_float4(a0, a1, a2, a3);
    __syncthreads();

    // store: thread t -> bl = t/4, r-quad = (t%4)*4; float4 along r.
    // 4-thread groups cover the full 64B line [r0, r0+16) -> line-coalesced.
    const int rq = (threadIdx.x & 3) * 4;
    const int bl = threadIdx.x >> 2;             // 0..255
    const int b = blockIdx.y * BCH + bl;
    const float4 bv = *reinterpret_cast<const float4*>(&bias[r0 + rq]);
    float4 o = make_float4(tile[rq + 0][bl] + bv.x, tile[rq + 1][bl] + bv.y,
                           tile[rq + 2][bl] + bv.z, tile[rq + 3][bl] + bv.w);
    *reinterpret_cast<float4*>(&out[(size_t)b * OUT_DIM + r0 + rq]) = o;
}

extern "C" void kernel_launch(void* const* d_in, const int* in_sizes, int n_in,
                              void* d_out, int out_size, void* d_ws, size_t ws_size,
                              hipStream_t stream) {
    const float* input   = (const float*)d_in[0];
    const int*   w_rows  = (const int*)d_in[1];
    const int*   w_cols  = (const int*)d_in[2];
    const float* w_vals  = (const float*)d_in[3];
    const int*   b_idx   = (const int*)d_in[4];
    const float* b_vals  = (const float*)d_in[5];
    float* out = (float*)d_out;

    char* ws = (char*)d_ws;
    const size_t MB = (size_t)1024 * 1024;
    unsigned short* inputT = (unsigned short*)ws;      // 4 MiB (bf16)
    float* bias   = (float*)(ws + 4 * MB);             // 16 KiB
    int*   counts = (int*)(ws + 4 * MB + 16 * 1024);   // 16 KiB
    int2*  slots  = (int2*)(ws + 4 * MB + 32 * 1024);  // 4096*160*8 = 5 MiB

    dim3 tb(32, 8);
    // zero_region = {bias, counts} contiguous 8192 ints, zeroed by first 32 blocks
    transpose_k<<<dim3(IN_DIM / 32, BATCH / 32), tb, 0, stream>>>(input, inputT,
                                                                  (int*)bias);

    build_k<<<(NNZ + 255) / 256, 256, 0, stream>>>(w_rows, w_cols, w_vals, counts,
                                                   slots, b_idx, b_vals, bias);

    spmm_k<<<dim3(OUT_DIM / RT, NCHUNK), 1024, 0, stream>>>(inputT, counts, slots,
                                                            bias, out);
}

// Round 15
// 58.990 us; speedup vs baseline: 1.9295x; 1.0911x over previous
//
#include <hip/hip_runtime.h>

#define OUT_DIM 4096
#define IN_DIM 4096
#define NNZ 327680
#define BNNZ 2048
#define BATCH 512
#define CAP 160            // max nnz slots/row (mean 80, sigma ~9; P(>160)~1e-19; held rounds 1-14)
#define RT 16              // rows per spmm block
#define TBLK 2048          // transpose blocks (128 x 16 tiles)
#define BBLK (NNZ / 256)   // build blocks = 1280

// fp32 -> bf16 round-to-nearest-even
__device__ __forceinline__ unsigned short f2bf(float f) {
    unsigned int x = __float_as_uint(f);
    x += 0x7fffu + ((x >> 16) & 1u);
    return (unsigned short)(x >> 16);
}

// ---- prep: block-specialized {transpose tiles} U {build slots + bias} -----
// Blocks [0,2048): transpose input [B,IN] f32 -> inputT [IN,B] bf16 (one
// 32x32 tile each). Blocks [2048, 3328): bucket 256 nnz each into per-row
// slot lists (counts zeroed by the preceding memset node); first 8 build
// blocks also scatter the sparse bias. The two groups are independent.
__global__ __launch_bounds__(256)
void prep_k(const float* __restrict__ in, unsigned short* __restrict__ outT,
            const int* __restrict__ rows, const int* __restrict__ cols,
            const float* __restrict__ vals, int* __restrict__ counts,
            int2* __restrict__ slots,
            const int* __restrict__ b_idx, const float* __restrict__ b_vals,
            float* __restrict__ bias) {
    const int bid = blockIdx.x;
    if (bid < TBLK) {
        __shared__ float tile[32][33];
        const int bx = (bid & 127) << 5;   // along IN
        const int by = (bid >> 7) << 5;    // along B
        const int tx = threadIdx.x & 31, ty = threadIdx.x >> 5;
        for (int i = ty; i < 32; i += 8)
            tile[i][tx] = in[(size_t)(by + i) * IN_DIM + bx + tx];
        __syncthreads();
        for (int i = ty; i < 32; i += 8)
            outT[(size_t)(bx + i) * BATCH + by + tx] = f2bf(tile[tx][i]);
    } else {
        const int bb = bid - TBLK;
        const int k = bb * 256 + threadIdx.x;          // 0..NNZ-1 exactly
        const int r = rows[k];
        const int p = atomicAdd(&counts[r], 1);
        if (p < CAP)   // byte offset into bf16 inputT row: col * BATCH * 2
            slots[(size_t)r * CAP + p] = make_int2(cols[k] * (BATCH * 2),
                                                   __float_as_int(vals[k]));
        if (bb < BNNZ / 256)                           // 8 blocks cover bias
            atomicAdd(&bias[b_idx[k]], b_vals[k]);
    }
}

// --- SpMM: byte-identical to rounds 6/10 (best known: 26 us) ---------------
// block = 16 rows x 512 b (1024 thr); wave = 1 row, lane = 8 b; dwordx4
// gather (1 instr / nnz, 16 lines); LDS-transposed line-coalesced stores.
__global__ __launch_bounds__(1024, 4)
void spmm_k(const unsigned short* __restrict__ inputT, const int* __restrict__ counts,
            const int2* __restrict__ slots, const float* __restrict__ bias,
            float* __restrict__ out) {
    const int w = threadIdx.x >> 6;      // wave = row within block
    const int lane = threadIdx.x & 63;   // lane = 8 batch elems
    const int r0 = blockIdx.x * RT;
    const int r = r0 + w;

    __shared__ int2  s_slot[RT][CAP];    // 20 KB, wave-private rows
    __shared__ float tile[RT][BATCH];    // 32 KB

    const int cnt = min(counts[r], CAP);
    for (int i = lane; i < cnt; i += 64)
        s_slot[w][i] = slots[(size_t)r * CAP + i];
    // no barrier: wave-private slot rows

    const char* base = (const char*)inputT + lane * 16;

    float a0 = 0.f, a1 = 0.f, a2 = 0.f, a3 = 0.f;
    float a4 = 0.f, a5 = 0.f, a6 = 0.f, a7 = 0.f;
#pragma unroll 4
    for (int j = 0; j < cnt; ++j) {
        const int2 sv = s_slot[w][j];
        const uint4 q = *reinterpret_cast<const uint4*>(base + sv.x);
        const float v = __int_as_float(sv.y);
        a0 = fmaf(v, __uint_as_float(q.x << 16), a0);
        a1 = fmaf(v, __uint_as_float(q.x & 0xffff0000u), a1);
        a2 = fmaf(v, __uint_as_float(q.y << 16), a2);
        a3 = fmaf(v, __uint_as_float(q.y & 0xffff0000u), a3);
        a4 = fmaf(v, __uint_as_float(q.z << 16), a4);
        a5 = fmaf(v, __uint_as_float(q.z & 0xffff0000u), a5);
        a6 = fmaf(v, __uint_as_float(q.w << 16), a6);
        a7 = fmaf(v, __uint_as_float(q.w & 0xffff0000u), a7);
    }
    float4* tp = reinterpret_cast<float4*>(&tile[w][lane * 8]);
    tp[0] = make_float4(a0, a1, a2, a3);
    tp[1] = make_float4(a4, a5, a6, a7);
    __syncthreads();

    // store: thread t -> b = t/4 (+256*k2), r-quad = (t%4)*4; float4 along r.
    // 4-thread groups cover the full 64B line [r0, r0+16) -> line-coalesced.
    const int rq = (threadIdx.x & 3) * 4;
    const float4 bv = *reinterpret_cast<const float4*>(&bias[r0 + rq]);
#pragma unroll
    for (int k2 = 0; k2 < 2; ++k2) {
        const int b = (threadIdx.x >> 2) + k2 * 256;
        float4 o = make_float4(tile[rq + 0][b] + bv.x, tile[rq + 1][b] + bv.y,
                               tile[rq + 2][b] + bv.z, tile[rq + 3][b] + bv.w);
        *reinterpret_cast<float4*>(&out[(size_t)b * OUT_DIM + r0 + rq]) = o;
    }
}

extern "C" void kernel_launch(void* const* d_in, const int* in_sizes, int n_in,
                              void* d_out, int out_size, void* d_ws, size_t ws_size,
                              hipStream_t stream) {
    const float* input   = (const float*)d_in[0];
    const int*   w_rows  = (const int*)d_in[1];
    const int*   w_cols  = (const int*)d_in[2];
    const float* w_vals  = (const float*)d_in[3];
    const int*   b_idx   = (const int*)d_in[4];
    const float* b_vals  = (const float*)d_in[5];
    float* out = (float*)d_out;

    char* ws = (char*)d_ws;
    const size_t MB = (size_t)1024 * 1024;
    unsigned short* inputT = (unsigned short*)ws;      // 4 MiB (bf16)
    float* bias   = (float*)(ws + 4 * MB);             // 16 KiB
    int*   counts = (int*)(ws + 4 * MB + 16 * 1024);   // 16 KiB
    int2*  slots  = (int2*)(ws + 4 * MB + 32 * 1024);  // 4096*160*8 = 5 MiB

    // zero bias + counts (DMA fill node; orders before prep_k on the stream)
    hipMemsetAsync(ws + 4 * MB, 0, 32 * 1024, stream);

    prep_k<<<TBLK + BBLK, 256, 0, stream>>>(input, inputT, w_rows, w_cols, w_vals,
                                            counts, slots, b_idx, b_vals, bias);

    spmm_k<<<OUT_DIM / RT, 1024, 0, stream>>>(inputT, counts, slots, bias, out);
}